// Round 11
// baseline (1159.338 us; speedup 1.0000x reference)
//
#include <hip/hip_runtime.h>

#define N_NODES 100000
#define N_EDGES 1200000
#define D 64
#define KEEP_PROB 0.7f
#define INV_KEEP (1.0f / KEEP_PROB)
#define NBUCK 1564         // ceil-ish(N_NODES/64) row-range buckets (row >> 6)
#define HIST_BLOCKS 256

#define ALOAD_I(p)   __hip_atomic_load((p), __ATOMIC_RELAXED, __HIP_MEMORY_SCOPE_AGENT)
#define ALOAD_U64(p) __hip_atomic_load((p), __ATOMIC_RELAXED, __HIP_MEMORY_SCOPE_AGENT)

// ---------------------------------------------------------------------------
__global__ __launch_bounds__(256) void zero_kernel(float4* __restrict__ p, int n4) {
    int i = blockIdx.x * 256 + threadIdx.x;
    if (i < n4) p[i] = make_float4(0.f, 0.f, 0.f, 0.f);
}
__global__ __launch_bounds__(256) void zero_ints_kernel(int* __restrict__ p, int n) {
    int i = blockIdx.x * 256 + threadIdx.x;
    if (i < n) p[i] = 0;
}

// ---------------------------------------------------------------------------
// Build 1 (R9-proven): per-bucket counts via per-block LDS histogram.
__global__ __launch_bounds__(256) void bucket_hist_kernel(const int4* __restrict__ rows4,
                                                          int* __restrict__ bcnt) {
    __shared__ int h[NBUCK];
    int t = threadIdx.x;
    for (int i = t; i < NBUCK; i += 256) h[i] = 0;
    __syncthreads();
    const int total = N_EDGES / 4;
    for (int i = blockIdx.x * 256 + t; i < total; i += HIST_BLOCKS * 256) {
        int4 r = rows4[i];
        atomicAdd(&h[r.x >> 6], 1);
        atomicAdd(&h[r.y >> 6], 1);
        atomicAdd(&h[r.z >> 6], 1);
        atomicAdd(&h[r.w >> 6], 1);
    }
    __syncthreads();
    for (int i = t; i < NBUCK; i += 256) {
        int c = h[i];
        if (c) atomicAdd(&bcnt[i << 4], c);   // 64B-strided counters
    }
}

// ---------------------------------------------------------------------------
// Build 2 (R9-proven): single-block exclusive scan of NBUCK strided counts
// -> bbase (deterministic, plain-readable) + strided cursor init.
__global__ __launch_bounds__(256) void bucket_scan_kernel(const int* __restrict__ bcnt,
                                                          int* __restrict__ bbase,
                                                          int* __restrict__ bcur) {
    __shared__ int part[256];
    const int CH = 7;   // 256*7 = 1792 >= NBUCK
    int t = threadIdx.x;
    int e[CH]; int s = 0;
    #pragma unroll
    for (int k = 0; k < CH; ++k) {
        int j = t * CH + k;
        e[k] = (j < NBUCK) ? ALOAD_I(&bcnt[j << 4]) : 0;
        s += e[k];
    }
    part[t] = s;
    __syncthreads();
    for (int d = 1; d < 256; d <<= 1) {
        int w = (t >= d) ? part[t - d] : 0;
        __syncthreads();
        part[t] += w;
        __syncthreads();
    }
    int run = part[t] - s;
    #pragma unroll
    for (int k = 0; k < CH; ++k) {
        int j = t * CH + k;
        if (j < NBUCK) { bbase[j] = run; bcur[j << 4] = run; run += e[k]; }
    }
    if (t == 255) bbase[NBUCK] = run;   // == N_EDGES
}

// ---------------------------------------------------------------------------
// Build 3 (R9 + meta packing): partition edges into buckets.
// Record: (meta, v0, meta, v1), meta = col | (localrow << 17)  [col < 2^17].
// Each layer's gather reads one contiguous 8B (meta, vL) pair.
__global__ __launch_bounds__(256) void partition_kernel(
    const int4*   __restrict__ rows4,
    const int4*   __restrict__ cols4,
    const float4* __restrict__ vals4,
    const float4* __restrict__ u04,
    const float4* __restrict__ u14,
    int*          __restrict__ bcur,
    uint4*        __restrict__ edata) {
    int i = blockIdx.x * 256 + threadIdx.x;
    if (i >= N_EDGES / 4) return;
    int4   r  = rows4[i];
    int4   c  = cols4[i];
    float4 v  = vals4[i];
    float4 u0 = u04[i];
    float4 u1 = u14[i];

    int p0 = atomicAdd(&bcur[(r.x >> 6) << 4], 1);
    int p1 = atomicAdd(&bcur[(r.y >> 6) << 4], 1);
    int p2 = atomicAdd(&bcur[(r.z >> 6) << 4], 1);
    int p3 = atomicAdd(&bcur[(r.w >> 6) << 4], 1);

    uint4 rec; float vv; unsigned meta;
    vv = v.x * INV_KEEP;
    meta = (unsigned)c.x | (((unsigned)r.x & 63u) << 17);
    rec.x = meta; rec.z = meta;
    rec.y = __float_as_uint((u0.x + KEEP_PROB >= 1.0f) ? vv : 0.f);
    rec.w = __float_as_uint((u1.x + KEEP_PROB >= 1.0f) ? vv : 0.f);
    edata[p0] = rec;
    vv = v.y * INV_KEEP;
    meta = (unsigned)c.y | (((unsigned)r.y & 63u) << 17);
    rec.x = meta; rec.z = meta;
    rec.y = __float_as_uint((u0.y + KEEP_PROB >= 1.0f) ? vv : 0.f);
    rec.w = __float_as_uint((u1.y + KEEP_PROB >= 1.0f) ? vv : 0.f);
    edata[p1] = rec;
    vv = v.z * INV_KEEP;
    meta = (unsigned)c.z | (((unsigned)r.z & 63u) << 17);
    rec.x = meta; rec.z = meta;
    rec.y = __float_as_uint((u0.z + KEEP_PROB >= 1.0f) ? vv : 0.f);
    rec.w = __float_as_uint((u1.z + KEEP_PROB >= 1.0f) ? vv : 0.f);
    edata[p2] = rec;
    vv = v.w * INV_KEEP;
    meta = (unsigned)c.w | (((unsigned)r.w & 63u) << 17);
    rec.x = meta; rec.z = meta;
    rec.y = __float_as_uint((u0.w + KEEP_PROB >= 1.0f) ? vv : 0.f);
    rec.w = __float_as_uint((u1.w + KEEP_PROB >= 1.0f) ? vv : 0.f);
    edata[p3] = rec;
}

// ---------------------------------------------------------------------------
// Bucket-level gather SpMM: one block per bucket (64 rows), LDS acc[64][64].
// Records are UNSORTED within the bucket (no finalize pass needed): each wave
// streams records, 64 lanes gather one x row, LDS f32 atomicAdd into the
// record's local row (conflict-free: 64 consecutive floats). No accumulator
// dependency -> iterations independent -> deep MLP.
// layer 0: io[row] = acc ; layer 1: io[row] = (io[row] + acc) / 3
__global__ __launch_bounds__(256) void spmm_bucket_kernel(
    const float* __restrict__ x_in,
    const unsigned long long* __restrict__ edata64,  // 2 u64 per edge
    const int*   __restrict__ bbase,                 // NBUCK+1, deterministic
    float4*      __restrict__ io4,
    int layer) {
    __shared__ float acc[64 * 64];   // 16 KB
    int b = blockIdx.x;
    int t = threadIdx.x;
    int wave = t >> 6;
    int lane = t & 63;
    int base = bbase[b];
    int size = bbase[b + 1] - base;

    for (int i = t; i < 64 * 64; i += 256) acc[i] = 0.f;
    __syncthreads();

    #pragma unroll 4
    for (int i = wave; i < size; i += 4) {
        unsigned long long rec = ALOAD_U64(&edata64[2 * (base + i) + layer]);
        unsigned meta = (unsigned)rec;
        float v = __uint_as_float((unsigned)(rec >> 32));
        int col  = (int)(meta & 0x1FFFFu);
        int lrow = (int)(meta >> 17);
        int cc = (v != 0.f) ? col : 0;          // dropped -> hot row 0
        float x = x_in[(cc << 6) + lane];
        atomicAdd(&acc[(lrow << 6) + lane], v * x);
    }
    __syncthreads();

    // write out 64 rows (16 float4 per row)
    const float4* acc4 = (const float4*)acc;
    int r0 = b << 6;
    for (int i = t; i < 1024; i += 256) {
        int row = r0 + (i >> 4);
        if (row < N_NODES) {
            float4 a = acc4[i];
            int o = (row << 4) + (i & 15);
            if (layer == 0) {
                io4[o] = a;
            } else {
                float4 p = io4[o];
                p.x = (p.x + a.x) * (1.0f / 3.0f);
                p.y = (p.y + a.y) * (1.0f / 3.0f);
                p.z = (p.z + a.z) * (1.0f / 3.0f);
                p.w = (p.w + a.w) * (1.0f / 3.0f);
                io4[o] = p;
            }
        }
    }
}

// ---------------------------------------------------------------------------
// out[n,j] = b[j] + sum_k emb[n,k]*W[j,k] + x1[n,j]
__global__ __launch_bounds__(256) void fc_add_kernel(
    const float* __restrict__ emb,
    const float* __restrict__ W,
    const float* __restrict__ b,
    const float* __restrict__ x1,
    float*       __restrict__ out) {
    __shared__ float Ws[D * 65];
    __shared__ float Es[4 * D];

    int t = threadIdx.x;
    #pragma unroll
    for (int i = 0; i < 16; ++i) {
        int idx = i * 256 + t;
        Ws[(idx >> 6) * 65 + (idx & 63)] = W[idx];
    }
    int node0 = blockIdx.x * 4;
    Es[t] = emb[node0 * D + t];
    __syncthreads();

    int local = t >> 6;
    int j     = t & 63;
    int n     = node0 + local;

    float acc = b[j];
    const float* es = &Es[local * D];
    const float* ws = &Ws[j * 65];
    #pragma unroll
    for (int k = 0; k < D; ++k) acc += es[k] * ws[k];
    out[n * D + j] = acc + x1[n * D + j];
}

// ---------------------------------------------------------------------------
// Fallback (atomic path, replay-proven) if ws too small
__global__ __launch_bounds__(256) void spmm_atomic_kernel(
    const float* __restrict__ x_in,
    const float* __restrict__ vals,
    const float* __restrict__ drop_u,
    const int*   __restrict__ rows,
    const int*   __restrict__ cols,
    float*       __restrict__ x_out) {
    int wave = (blockIdx.x * 256 + threadIdx.x) >> 6;
    int lane = threadIdx.x & 63;
    if (wave >= N_EDGES) return;
    float u = drop_u[wave];
    if (u + KEEP_PROB < 1.0f) return;
    float v = vals[wave] * INV_KEEP;
    atomicAdd(&x_out[rows[wave] * D + lane], v * x_in[cols[wave] * D + lane]);
}

__global__ __launch_bounds__(256) void scale_kernel(float4* __restrict__ p, int n4) {
    int i = blockIdx.x * 256 + threadIdx.x;
    if (i < n4) {
        float4 v = p[i];
        v.x *= (1.f/3.f); v.y *= (1.f/3.f); v.z *= (1.f/3.f); v.w *= (1.f/3.f);
        p[i] = v;
    }
}

// ---------------------------------------------------------------------------
extern "C" void kernel_launch(void* const* d_in, const int* in_sizes, int n_in,
                              void* d_out, int out_size, void* d_ws, size_t ws_size,
                              hipStream_t stream) {
    const float* all_emb = (const float*)d_in[0];
    const float* W       = (const float*)d_in[1];
    const float* b       = (const float*)d_in[2];
    const float* vals    = (const float*)d_in[3];
    const float* drop_u  = (const float*)d_in[4];   // [2, E]
    const int*   rows    = (const int*)d_in[5];
    const int*   cols    = (const int*)d_in[6];

    float* out = (float*)d_out;

    // workspace layout (64B aligned)
    char* ws = (char*)d_ws;
    float* x1    = (float*)(ws);                    // 25,600,000 B
    uint4* edata = (uint4*)(ws + 25600000);         // 19,200,000 B
    int*   bcnt  = (int*)  (ws + 44800000);         //    100,096 B (NBUCK x 64B)
    int*   bbase = (int*)  (ws + 44900096);         //      6,272 B (NBUCK+1)
    int*   bcur  = (int*)  (ws + 44906368);         //    100,096 B (NBUCK x 64B)
    const size_t WS_NEEDED = 45006464;              // < 45.45MB proven available (R10)

    const int n4 = N_NODES * D / 4;
    const int zb = (n4 + 255) / 256;
    const int e4_blocks = (N_EDGES / 4 + 255) / 256;      // 1172

    if (ws_size >= WS_NEEDED) {
        zero_ints_kernel<<<(NBUCK * 16 + 255) / 256, 256, 0, stream>>>(bcnt, NBUCK * 16);
        bucket_hist_kernel<<<HIST_BLOCKS, 256, 0, stream>>>((const int4*)rows, bcnt);
        bucket_scan_kernel<<<1, 256, 0, stream>>>(bcnt, bbase, bcur);
        partition_kernel<<<e4_blocks, 256, 0, stream>>>(
            (const int4*)rows, (const int4*)cols, (const float4*)vals,
            (const float4*)drop_u, (const float4*)(drop_u + N_EDGES),
            bcur, edata);
        // layer 0: x1 = A1 @ all_emb   (writes every row: no pre-zero needed)
        spmm_bucket_kernel<<<NBUCK, 256, 0, stream>>>(
            all_emb, (const unsigned long long*)edata, bbase, (float4*)x1, 0);
        // out = fc(all_emb) + x1
        fc_add_kernel<<<N_NODES / 4, 256, 0, stream>>>(all_emb, W, b, x1, out);
        // layer 1 (fused /3): out = (out + A2 @ x1) / 3
        spmm_bucket_kernel<<<NBUCK, 256, 0, stream>>>(
            x1, (const unsigned long long*)edata, bbase, (float4*)out, 1);
    } else {
        // fallback: proven atomic path
        const int spmm_blocks = (N_EDGES + 3) / 4;
        zero_kernel<<<zb, 256, 0, stream>>>((float4*)x1, n4);
        spmm_atomic_kernel<<<spmm_blocks, 256, 0, stream>>>(all_emb, vals, drop_u,
                                                            rows, cols, x1);
        fc_add_kernel<<<N_NODES / 4, 256, 0, stream>>>(all_emb, W, b, x1, out);
        spmm_atomic_kernel<<<spmm_blocks, 256, 0, stream>>>(x1, vals,
                                                            drop_u + N_EDGES,
                                                            rows, cols, out);
        scale_kernel<<<zb, 256, 0, stream>>>((float4*)out, n4);
    }
}